// Round 1
// baseline (13865.598 us; speedup 1.0000x reference)
//
#include <hip/hip_runtime.h>
#include <hip/hip_bf16.h>
#include <math.h>

// Model constants
#define H_    768
#define NH_   12
#define NKV_  4
#define HD_   64
#define IM_   3072
#define KCONV 4
#define EPS_  1e-6f
#define B_    2
#define S_    1024
#define BS_   2048   // B*S
#define V_    50304

// ---------------------------------------------------------------------------
// Embedding lookup: x[bs, :] = embed[tok[bs], :]
__global__ void embed_kernel(const int* __restrict__ tok,
                             const float* __restrict__ emb,
                             float* __restrict__ x) {
    int bs = blockIdx.x;
    int t = threadIdx.x;
    int tk = tok[bs];
    const float* e = emb + (size_t)tk * H_;
    float* xr = x + (size_t)bs * H_;
    xr[t]       = e[t];
    xr[t + 256] = e[t + 256];
    xr[t + 512] = e[t + 512];
}

// ---------------------------------------------------------------------------
// RMSNorm over rows of length 768. One block (256 thr) per row.
__global__ void rmsnorm768(const float* __restrict__ x,
                           const float* __restrict__ w,
                           float* __restrict__ y) {
    int row = blockIdx.x;
    int t = threadIdx.x;
    const float* xr = x + (size_t)row * H_;
    float v0 = xr[t], v1 = xr[t + 256], v2 = xr[t + 512];
    __shared__ float red[256];
    red[t] = v0 * v0 + v1 * v1 + v2 * v2;
    __syncthreads();
    for (int o = 128; o > 0; o >>= 1) {
        if (t < o) red[t] += red[t + o];
        __syncthreads();
    }
    float inv = rsqrtf(red[0] / (float)H_ + EPS_);
    float* yr = y + (size_t)row * H_;
    yr[t]       = v0 * inv * w[t];
    yr[t + 256] = v1 * inv * w[t + 256];
    yr[t + 512] = v2 * inv * w[t + 512];
}

// ---------------------------------------------------------------------------
// RMSNorm over rows of length 64 (per-head q/k norm), in place.
// One wave per row, 4 rows per block.
__global__ void rmsnorm_head(float* __restrict__ x,
                             const float* __restrict__ w, int rows) {
    int lane = threadIdx.x & 63;
    int wv = threadIdx.x >> 6;
    int row = blockIdx.x * 4 + wv;
    if (row >= rows) return;
    float* xr = x + (size_t)row * HD_;
    float v = xr[lane];
    float ss = v * v;
    for (int o = 32; o > 0; o >>= 1) ss += __shfl_xor(ss, o);
    float inv = rsqrtf(ss / (float)HD_ + EPS_);
    xr[lane] = v * inv * w[lane];
}

// ---------------------------------------------------------------------------
// RoPE in place on [B,S,nh,64]. One thread per (row, d<32) pair.
__global__ void rope_kernel(float* __restrict__ x, int nh) {
    size_t idx = (size_t)blockIdx.x * 256 + threadIdx.x;
    size_t total = (size_t)BS_ * nh * 32;
    if (idx >= total) return;
    int d = (int)(idx & 31);
    size_t rest = idx >> 5;
    int h = (int)(rest % nh);
    size_t bs = rest / nh;
    int s = (int)(bs & (S_ - 1));
    float inv = powf(10000.0f, -(float)(2 * d) / (float)HD_);
    float ang = (float)s * inv;
    float c = cosf(ang), sn = sinf(ang);
    float* p = x + (bs * nh + h) * HD_;
    float x0 = p[d], x1 = p[d + 32];
    p[d]      = x0 * c - x1 * sn;
    p[d + 32] = x1 * c + x0 * sn;
}

// ---------------------------------------------------------------------------
// Fused causal GQA attention, one block (256 thr) per query row.
// q: [B,S,NH,64]  k,v: [B,S,NKV,64]  o: [B,S,NH,64]
__global__ __launch_bounds__(256) void attn_kernel(
        const float* __restrict__ q, const float* __restrict__ k,
        const float* __restrict__ v, float* __restrict__ o) {
    int row = blockIdx.x;               // b*NH*S + h*S + i
    int i = row & (S_ - 1);
    int h = (row >> 10) % NH_;
    int b = row / (S_ * NH_);
    int kh = h / (NH_ / NKV_);
    int t = threadIdx.x;

    __shared__ float qs[HD_];
    __shared__ float sc[S_];
    __shared__ float red[256];

    const float* qrow = q + ((size_t)(b * S_ + i) * NH_ + h) * HD_;
    if (t < HD_) qs[t] = qrow[t];
    __syncthreads();

    // scores for j <= i
    for (int j = t; j <= i; j += 256) {
        const float4* k4 = (const float4*)(k + ((size_t)(b * S_ + j) * NKV_ + kh) * HD_);
        float s = 0.f;
#pragma unroll
        for (int d4 = 0; d4 < HD_ / 4; d4++) {
            float4 kv = k4[d4];
            s += qs[4 * d4 + 0] * kv.x + qs[4 * d4 + 1] * kv.y +
                 qs[4 * d4 + 2] * kv.z + qs[4 * d4 + 3] * kv.w;
        }
        sc[j] = s * 0.125f;   // 1/sqrt(64)
    }
    __syncthreads();

    // max
    float m = -1e30f;
    for (int j = t; j <= i; j += 256) m = fmaxf(m, sc[j]);
    red[t] = m; __syncthreads();
    for (int off = 128; off > 0; off >>= 1) {
        if (t < off) red[t] = fmaxf(red[t], red[t + off]);
        __syncthreads();
    }
    m = red[0];
    __syncthreads();

    // exp + sum
    float ssum = 0.f;
    for (int j = t; j <= i; j += 256) {
        float e = expf(sc[j] - m);
        sc[j] = e;
        ssum += e;
    }
    red[t] = ssum; __syncthreads();
    for (int off = 128; off > 0; off >>= 1) {
        if (t < off) red[t] += red[t + off];
        __syncthreads();
    }
    float inv = 1.0f / red[0];
    __syncthreads();

    // weighted sum of v. threads = (dt 0..63) x (g 0..3)
    int dt = t & 63, g = t >> 6;
    float acc = 0.f;
    for (int j = g; j <= i; j += 4) {
        acc += sc[j] * v[((size_t)(b * S_ + j) * NKV_ + kh) * HD_ + dt];
    }
    red[t] = acc; __syncthreads();
    if (g == 0) {
        float r = red[dt] + red[64 + dt] + red[128 + dt] + red[192 + dt];
        o[((size_t)(b * S_ + i) * NH_ + h) * HD_ + dt] = r * inv;
    }
}

// ---------------------------------------------------------------------------
// Causal depthwise conv gating. bcx: [B,S,3H] (Bg|Cg|xg), y: [B,S,H]
// y[b,s,c] = Cg[b,s,c] * ( sum_t cw[c,t]*Bg[b,s-3+t,c]*xg[b,s-3+t,c] + cb[c] )
__global__ void conv_kernel(const float* __restrict__ bcx,
                            const float* __restrict__ cw,
                            const float* __restrict__ cb,
                            float* __restrict__ y) {
    size_t idx = (size_t)blockIdx.x * 256 + threadIdx.x;
    if (idx >= (size_t)BS_ * H_) return;
    int c = (int)(idx % H_);
    size_t bs = idx / H_;
    int s = (int)(bs & (S_ - 1));
    int b = (int)(bs >> 10);
    const float* base = bcx + (size_t)b * S_ * (3 * H_);
    float conv = cb[c];
#pragma unroll
    for (int t = 0; t < KCONV; t++) {
        int sp = s - (KCONV - 1) + t;
        if (sp >= 0) {
            float Bg = base[(size_t)sp * (3 * H_) + c];
            float xg = base[(size_t)sp * (3 * H_) + 2 * H_ + c];
            conv += cw[c * KCONV + t] * (Bg * xg);
        }
    }
    float Cg = base[(size_t)s * (3 * H_) + H_ + c];
    y[idx] = Cg * conv;
}

// ---------------------------------------------------------------------------
// g = silu(g) * u, elementwise
__global__ void silu_mul(float* __restrict__ g, const float* __restrict__ u,
                         size_t n) {
    size_t i = (size_t)blockIdx.x * 256 + threadIdx.x;
    if (i < n) {
        float a = g[i];
        g[i] = (a / (1.0f + expf(-a))) * u[i];
    }
}

// ---------------------------------------------------------------------------
// Tiled fp32 NT GEMM: C[M,N] = A[M,K] * W[N,K]^T (+ bias[n]) (+ resid[m,n])
// 64x64 tile, 256 threads, 4x4 microtile, K-transposed LDS (b128 frag loads).
// Requires M%64==0, N%64==0, K%16==0.
__global__ __launch_bounds__(256) void gemm_nt(
        const float* __restrict__ A, const float* __restrict__ W,
        const float* __restrict__ bias, const float* __restrict__ resid,
        float* __restrict__ C, int M, int N, int K) {
    __shared__ float As[16][68];
    __shared__ float Ws[16][68];
    int tid = threadIdx.x;
    int tx = tid & 15, ty = tid >> 4;
    int bm = blockIdx.y * 64, bn = blockIdx.x * 64;
    int r = ty, c = tx;
    float acc[4][4] = {};

    for (int k0 = 0; k0 < K; k0 += 16) {
#pragma unroll
        for (int rr = 0; rr < 4; rr++) {
            As[c][r + 16 * rr] = A[(size_t)(bm + r + 16 * rr) * K + k0 + c];
            Ws[c][r + 16 * rr] = W[(size_t)(bn + r + 16 * rr) * K + k0 + c];
        }
        __syncthreads();
#pragma unroll
        for (int kk = 0; kk < 16; kk++) {
            float4 a4 = *(const float4*)&As[kk][ty * 4];
            float4 w4 = *(const float4*)&Ws[kk][tx * 4];
            float av[4] = {a4.x, a4.y, a4.z, a4.w};
            float wv[4] = {w4.x, w4.y, w4.z, w4.w};
#pragma unroll
            for (int i = 0; i < 4; i++)
#pragma unroll
                for (int j = 0; j < 4; j++) acc[i][j] += av[i] * wv[j];
        }
        __syncthreads();
    }

#pragma unroll
    for (int i = 0; i < 4; i++) {
        int m = bm + ty * 4 + i;
        float4 out;
        float* op = (float*)&out;
#pragma unroll
        for (int j = 0; j < 4; j++) {
            int n = bn + tx * 4 + j;
            float val = acc[i][j];
            if (bias)  val += bias[n];
            if (resid) val += resid[(size_t)m * N + n];
            op[j] = val;
        }
        *(float4*)&C[(size_t)m * N + bn + tx * 4] = out;
    }
}

// ---------------------------------------------------------------------------
static inline void gemm(const float* A, const float* W, const float* bias,
                        const float* resid, float* C, int M, int N, int K,
                        hipStream_t st) {
    dim3 grid(N / 64, M / 64);
    gemm_nt<<<grid, 256, 0, st>>>(A, W, bias, resid, C, M, N, K);
}

extern "C" void kernel_launch(void* const* d_in, const int* in_sizes, int n_in,
                              void* d_out, int out_size, void* d_ws, size_t ws_size,
                              hipStream_t stream) {
    const int*   tokens  = (const int*)d_in[0];
    const float* embed   = (const float*)d_in[1];
    const float* qw      = (const float*)d_in[2];
    const float* kw      = (const float*)d_in[3];
    const float* vw      = (const float*)d_in[4];
    const float* ow      = (const float*)d_in[5];
    const float* qln     = (const float*)d_in[6];
    const float* kln     = (const float*)d_in[7];
    const float* a_gate  = (const float*)d_in[8];
    const float* a_up    = (const float*)d_in[9];
    const float* a_down  = (const float*)d_in[10];
    const float* a_ln1   = (const float*)d_in[11];
    const float* a_ln2   = (const float*)d_in[12];
    const float* conv_w  = (const float*)d_in[13];
    const float* conv_b  = (const float*)d_in[14];
    const float* in_w    = (const float*)d_in[15];
    const float* in_b    = (const float*)d_in[16];
    const float* out_w   = (const float*)d_in[17];
    const float* out_b   = (const float*)d_in[18];
    const float* c_gate  = (const float*)d_in[19];
    const float* c_up    = (const float*)d_in[20];
    const float* c_down  = (const float*)d_in[21];
    const float* c_ln1   = (const float*)d_in[22];
    const float* c_ln2   = (const float*)d_in[23];
    const float* fin_ln  = (const float*)d_in[24];
    const float* lm_head = (const float*)d_in[25];

    // workspace layout (floats): x | h | s1 (BS*3072) | s2 (BS*3072)
    float* x  = (float*)d_ws;
    float* h  = x + (size_t)BS_ * H_;
    float* s1 = h + (size_t)BS_ * H_;
    float* s2 = s1 + (size_t)BS_ * IM_;

    embed_kernel<<<BS_, 256, 0, stream>>>(tokens, embed, x);

    int ai = 0, ci = 0;
    for (int l = 0; l < 12; l++) {
        bool full = (l == 2 || l == 5 || l == 8 || l == 11);
        if (full) {
            rmsnorm768<<<BS_, 256, 0, stream>>>(x, a_ln1 + (size_t)ai * H_, h);
            float* q = s1;
            float* k = s1 + (size_t)BS_ * H_;
            float* v = k + (size_t)BS_ * (NKV_ * HD_);
            gemm(h, qw + (size_t)ai * H_ * H_, nullptr, nullptr, q, BS_, H_, H_, stream);
            gemm(h, kw + (size_t)ai * NKV_ * HD_ * H_, nullptr, nullptr, k, BS_, NKV_ * HD_, H_, stream);
            gemm(h, vw + (size_t)ai * NKV_ * HD_ * H_, nullptr, nullptr, v, BS_, NKV_ * HD_, H_, stream);
            rmsnorm_head<<<(BS_ * NH_) / 4, 256, 0, stream>>>(q, qln + (size_t)ai * HD_, BS_ * NH_);
            rmsnorm_head<<<(BS_ * NKV_) / 4, 256, 0, stream>>>(k, kln + (size_t)ai * HD_, BS_ * NKV_);
            rope_kernel<<<(BS_ * NH_ * 32) / 256, 256, 0, stream>>>(q, NH_);
            rope_kernel<<<(BS_ * NKV_ * 32) / 256, 256, 0, stream>>>(k, NKV_);
            attn_kernel<<<B_ * NH_ * S_, 256, 0, stream>>>(q, k, v, s2);
            gemm(s2, ow + (size_t)ai * H_ * H_, nullptr, x, x, BS_, H_, H_, stream);
            rmsnorm768<<<BS_, 256, 0, stream>>>(x, a_ln2 + (size_t)ai * H_, h);
            gemm(h, a_gate + (size_t)ai * IM_ * H_, nullptr, nullptr, s1, BS_, IM_, H_, stream);
            gemm(h, a_up + (size_t)ai * IM_ * H_, nullptr, nullptr, s2, BS_, IM_, H_, stream);
            silu_mul<<<(BS_ * IM_) / 256, 256, 0, stream>>>(s1, s2, (size_t)BS_ * IM_);
            gemm(s1, a_down + (size_t)ai * H_ * IM_, nullptr, x, x, BS_, H_, IM_, stream);
            ai++;
        } else {
            rmsnorm768<<<BS_, 256, 0, stream>>>(x, c_ln1 + (size_t)ci * H_, h);
            gemm(h, in_w + (size_t)ci * 3 * H_ * H_, in_b + (size_t)ci * 3 * H_, nullptr,
                 s1, BS_, 3 * H_, H_, stream);
            conv_kernel<<<(BS_ * H_) / 256, 256, 0, stream>>>(
                s1, conv_w + (size_t)ci * H_ * KCONV, conv_b + (size_t)ci * H_, s2);
            gemm(s2, out_w + (size_t)ci * H_ * H_, out_b + (size_t)ci * H_, x, x, BS_, H_, H_, stream);
            rmsnorm768<<<BS_, 256, 0, stream>>>(x, c_ln2 + (size_t)ci * H_, h);
            gemm(h, c_gate + (size_t)ci * IM_ * H_, nullptr, nullptr, s1, BS_, IM_, H_, stream);
            gemm(h, c_up + (size_t)ci * IM_ * H_, nullptr, nullptr, s2, BS_, IM_, H_, stream);
            silu_mul<<<(BS_ * IM_) / 256, 256, 0, stream>>>(s1, s2, (size_t)BS_ * IM_);
            gemm(s1, c_down + (size_t)ci * H_ * IM_, nullptr, x, x, BS_, H_, IM_, stream);
            ci++;
        }
    }

    rmsnorm768<<<BS_, 256, 0, stream>>>(x, fin_ln, h);
    gemm(h, lm_head, nullptr, nullptr, (float*)d_out, BS_, V_, H_, stream);
}